// Round 14
// baseline (1900.535 us; speedup 1.0000x reference)
//
#include <hip/hip_runtime.h>
#include <math.h>

// Residual SF-DiVeQ (N=65536, D=64, C=4, K=1024) — bit-exact numpy-fp32 argmin.
// R14 = R12 resubmitted verbatim again (R12+R13 both died on
// UnresponsiveContainer — infra failures, no kernel signal).
//  - prep builds cbT[c][d][k] (fp32 transposed codebook, 4MB total)
//  - fixup lane=k reads cbT[d*K+k]: 64 lanes -> 64 consecutive floats =
//    one coalesced 256B transaction per d (R11: 64 distinct cache lines).
//  - fixup 4 waves/block (wave = one flagged row).
// Numerics identical: same fp32 values, same d-ascending fmaf chain, same
// (srr-2dot)+cn rounding, same u64 (bits(dd),k) first-index tie-break.

#define N_PTS 65536
#define DIM 64
#define NCB 4
#define KCB 1024
#define MARGIN 8e-5f

typedef unsigned long long u64;
typedef short  s16x8 __attribute__((ext_vector_type(8)));
typedef float  f32x4 __attribute__((ext_vector_type(4)));

__device__ __forceinline__ unsigned short bf16_rne(float x) {
    unsigned u = __float_as_uint(x);
    u += 0x7fffu + ((u >> 16) & 1u);
    return (unsigned short)(u >> 16);
}
__device__ __forceinline__ float bf16_val(unsigned short h) {
    return __uint_as_float(((unsigned)h) << 16);
}

// ---- prep: cn (numpy-pairwise fp32), cb splits, cbT transpose, zero counters
__global__ __launch_bounds__(256) void prep_kernel(const float* __restrict__ cb,
    float* __restrict__ cnp, unsigned short* __restrict__ cbh,
    unsigned short* __restrict__ cbl, float* __restrict__ cbT,
    int* __restrict__ counts, int* __restrict__ flagcnt)
{
#pragma clang fp contract(off)
    int t = blockIdx.x * 256 + threadIdx.x;       // grid 16 -> 4096 = C*K
    int c = t >> 10, k = t & 1023;
    const float* row = cb + (size_t)t * DIM;
    float pr[8];
#pragma unroll
    for (int j = 0; j < 8; ++j) { float v = row[j]; pr[j] = v * v; }
#pragma unroll
    for (int i = 8; i < DIM; i += 8)
#pragma unroll
        for (int j = 0; j < 8; ++j) { float v = row[i + j]; pr[j] += v * v; }
    cnp[t] = ((pr[0] + pr[1]) + (pr[2] + pr[3])) + ((pr[4] + pr[5]) + (pr[6] + pr[7]));
    counts[t] = 0;
#pragma unroll
    for (int d = 0; d < DIM; ++d) {
        float x = row[d];
        unsigned short h = bf16_rne(x);
        unsigned short l = bf16_rne(x - bf16_val(h));
        cbh[(size_t)t * DIM + d] = h;
        cbl[(size_t)t * DIM + d] = l;
        cbT[((size_t)c * DIM + d) * KCB + k] = x;   // transposed fp32 copy
    }
    if (t < NCB) flagcnt[t] = 0;
}

// ---------------- uprr: rem update (fp32 single-rounded) + splits + srr ------
__global__ __launch_bounds__(256) void uprr_kernel(
    const float* __restrict__ src, const float* __restrict__ cbc,
    const int* __restrict__ ixp, float* __restrict__ rem,
    unsigned short* __restrict__ remh, unsigned short* __restrict__ reml,
    float* __restrict__ srr)
{
#pragma clang fp contract(off)
    int lane = threadIdx.x & 63;
    int n = blockIdx.x * 4 + (threadIdx.x >> 6);   // grid 16384
    size_t e = (size_t)n * DIM + lane;
    float r = src[e];
    if (cbc) {
        int ix = ixp[n];                            // wave-uniform broadcast
        r = r - cbc[(size_t)ix * DIM + lane];       // single rounding
    }
    rem[e] = r;
    unsigned short h = bf16_rne(r);
    unsigned short l = bf16_rne(r - bf16_val(h));
    remh[e] = h; reml[e] = l;
    // exact numpy pairwise srr (verified shfl recipe)
    float sq = r * r;
    float pr = sq;
#pragma unroll
    for (int i = 1; i < 8; ++i) pr += __shfl(sq, (lane & 7) + 8 * i);
    pr += __shfl_xor(pr, 1);
    pr += __shfl_xor(pr, 2);
    pr += __shfl_xor(pr, 4);
    if (lane == 0) srr[n] = pr;
}

// ---------------- dist: MFMA bulk, (min1,min2) margin certification ----------
__global__ __launch_bounds__(256, 4) void dist_kernel(
    const unsigned short* __restrict__ remh, const unsigned short* __restrict__ reml,
    const unsigned short* __restrict__ cbh, const unsigned short* __restrict__ cbl,
    const float* __restrict__ cnp, const float* __restrict__ srr,
    int* __restrict__ idxc, int* __restrict__ flagcnt_c, int* __restrict__ flaglist)
{
    int lane = threadIdx.x & 63;
    int wv = threadIdx.x >> 6;
    int g = lane >> 4;                              // frag group 0..3
    int lc = lane & 15;
    int n0 = blockIdx.x * 128 + wv * 32;            // wave's 32 rows

    int ar0 = n0 + lc, ar1 = ar0 + 16;
    s16x8 Ah00 = *(const s16x8*)(remh + (size_t)ar0 * DIM + g * 8);
    s16x8 Ah01 = *(const s16x8*)(remh + (size_t)ar0 * DIM + 32 + g * 8);
    s16x8 Al00 = *(const s16x8*)(reml + (size_t)ar0 * DIM + g * 8);
    s16x8 Al01 = *(const s16x8*)(reml + (size_t)ar0 * DIM + 32 + g * 8);
    s16x8 Ah10 = *(const s16x8*)(remh + (size_t)ar1 * DIM + g * 8);
    s16x8 Ah11 = *(const s16x8*)(remh + (size_t)ar1 * DIM + 32 + g * 8);
    s16x8 Al10 = *(const s16x8*)(reml + (size_t)ar1 * DIM + g * 8);
    s16x8 Al11 = *(const s16x8*)(reml + (size_t)ar1 * DIM + 32 + g * 8);

    f32x4 srr0 = *(const f32x4*)(srr + n0 + g * 4);
    f32x4 srr1 = *(const f32x4*)(srr + n0 + 16 + g * 4);

    f32x4 m1_0 = (f32x4)3.4028235e38f, m2_0 = (f32x4)3.4028235e38f;
    f32x4 m1_1 = (f32x4)3.4028235e38f, m2_1 = (f32x4)3.4028235e38f;
    int ix0[4] = {0,0,0,0}, ix1[4] = {0,0,0,0};

    for (int t = 0; t < KCB / 16; ++t) {
        int col = t * 16 + lc;
        const unsigned short* bhp = cbh + (size_t)col * DIM + g * 8;
        const unsigned short* blp = cbl + (size_t)col * DIM + g * 8;
        s16x8 Bh0 = *(const s16x8*)(bhp);
        s16x8 Bh1 = *(const s16x8*)(bhp + 32);
        s16x8 Bl0 = *(const s16x8*)(blp);
        s16x8 Bl1 = *(const s16x8*)(blp + 32);
        float cnl = cnp[col];

        f32x4 za = (f32x4)0.0f, zb = (f32x4)0.0f;
        f32x4 a = __builtin_amdgcn_mfma_f32_16x16x32_bf16(Ah00, Bh0, za, 0, 0, 0);
        a = __builtin_amdgcn_mfma_f32_16x16x32_bf16(Al00, Bh0, a, 0, 0, 0);
        a = __builtin_amdgcn_mfma_f32_16x16x32_bf16(Ah00, Bl0, a, 0, 0, 0);
        f32x4 b = __builtin_amdgcn_mfma_f32_16x16x32_bf16(Ah01, Bh1, zb, 0, 0, 0);
        b = __builtin_amdgcn_mfma_f32_16x16x32_bf16(Al01, Bh1, b, 0, 0, 0);
        b = __builtin_amdgcn_mfma_f32_16x16x32_bf16(Ah01, Bl1, b, 0, 0, 0);
        f32x4 dot0 = a + b;
        f32x4 a1 = __builtin_amdgcn_mfma_f32_16x16x32_bf16(Ah10, Bh0, za, 0, 0, 0);
        a1 = __builtin_amdgcn_mfma_f32_16x16x32_bf16(Al10, Bh0, a1, 0, 0, 0);
        a1 = __builtin_amdgcn_mfma_f32_16x16x32_bf16(Ah10, Bl0, a1, 0, 0, 0);
        f32x4 b1 = __builtin_amdgcn_mfma_f32_16x16x32_bf16(Ah11, Bh1, zb, 0, 0, 0);
        b1 = __builtin_amdgcn_mfma_f32_16x16x32_bf16(Al11, Bh1, b1, 0, 0, 0);
        b1 = __builtin_amdgcn_mfma_f32_16x16x32_bf16(Ah11, Bl1, b1, 0, 0, 0);
        f32x4 dot1 = a1 + b1;

#pragma unroll
        for (int j = 0; j < 4; ++j) {
            float d2 = fmaf(dot0[j], -2.0f, srr0[j] + cnl);
            bool lt = d2 < m1_0[j];
            float mn2 = fminf(m2_0[j], d2);
            m2_0[j] = lt ? m1_0[j] : mn2;
            m1_0[j] = lt ? d2 : m1_0[j];
            ix0[j] = lt ? col : ix0[j];
        }
#pragma unroll
        for (int j = 0; j < 4; ++j) {
            float d2 = fmaf(dot1[j], -2.0f, srr1[j] + cnl);
            bool lt = d2 < m1_1[j];
            float mn2 = fminf(m2_1[j], d2);
            m2_1[j] = lt ? m1_1[j] : mn2;
            m1_1[j] = lt ? d2 : m1_1[j];
            ix1[j] = lt ? col : ix1[j];
        }
    }

#pragma unroll
    for (int rt = 0; rt < 2; ++rt) {
#pragma unroll
        for (int j = 0; j < 4; ++j) {
            float m1v = rt ? m1_1[j] : m1_0[j];
            float m2v = rt ? m2_1[j] : m2_0[j];
            int   ixv = rt ? ix1[j] : ix0[j];
            u64 key = ((u64)__float_as_uint(m1v) << 32) | (unsigned)ixv;
#pragma unroll
            for (int off = 1; off < 16; off <<= 1) {
                u64 ko = __shfl_xor(key, off);
                float m2o = __shfl_xor(m2v, off);
                u64 kmax = key > ko ? key : ko;
                key = key < ko ? key : ko;
                m2v = fminf(fminf(m2v, m2o), __uint_as_float((unsigned)(kmax >> 32)));
            }
            if (lc == 0) {
                int n = n0 + rt * 16 + g * 4 + j;
                idxc[n] = (int)(unsigned)(key & 0xffffffffu);
                float gap = m2v - __uint_as_float((unsigned)(key >> 32));
                if (!(gap >= MARGIN)) {
                    int p = atomicAdd(flagcnt_c, 1);
                    if (p < N_PTS) flaglist[p] = n;
                }
            }
        }
    }
}

// ---- fixup: exact numpy-fp32 rescan, coalesced via cbT; wave = flagged row --
__global__ __launch_bounds__(256) void fixup_kernel(
    const float* __restrict__ rem, const float* __restrict__ srr,
    const float* __restrict__ cbTc, const float* __restrict__ cnc,
    int* __restrict__ idxc,
    const int* __restrict__ flagcnt_c, const int* __restrict__ flaglist)
{
#pragma clang fp contract(off)
    __shared__ float rlds[4][DIM];
    int lane = threadIdx.x & 63;
    int wv = threadIdx.x >> 6;
    int cnt = *flagcnt_c; if (cnt > N_PTS) cnt = N_PTS;
    for (int i = blockIdx.x * 4 + wv; i < cnt; i += gridDim.x * 4) {
        int n = flaglist[i];
        rlds[wv][lane] = rem[(size_t)n * DIM + lane];
        float srrv = srr[n];
        // wave-local barrier not needed: LDS row written+read by same wave;
        // ds ops complete in order within a wave.
        u64 best = 0xffffffffffffffffull;
        for (int t = 0; t < KCB / 64; ++t) {
            int k = t * 64 + lane;
            float acc = 0.0f;
#pragma unroll
            for (int d = 0; d < DIM; ++d)            // lane-coalesced: 64 consec
                acc = fmaf(rlds[wv][d], cbTc[(size_t)d * KCB + k], acc);
            float t1 = 2.0f * acc;                   // exact
            float t2 = srrv - t1;                    // ref rounding order
            float dd = t2 + cnc[k];
            u64 key = ((u64)__float_as_uint(dd) << 32) | (unsigned)k;
            if (key < best) best = key;
        }
#pragma unroll
        for (int off = 1; off < 64; off <<= 1) {
            u64 o = __shfl_xor(best, off);
            if (o < best) best = o;
        }
        if (lane == 0) idxc[n] = (int)(unsigned)(best & 0xffffffffu);
    }
}

// ---------------- epilogue: z_q (fp64; threshold ~2% of magnitude) -----------
__global__ __launch_bounds__(256) void zq_kernel(
    const float* __restrict__ z, const float* __restrict__ noise,
    const float* __restrict__ cbase, const int* __restrict__ idxA,
    float* __restrict__ out)
{
    int lane = threadIdx.x & 63;
    int n = blockIdx.x * 4 + (threadIdx.x >> 6);   // grid 16384
    size_t e = (size_t)n * DIM + lane;
    double zd = z[e];
    double rd = zd;
#pragma unroll
    for (int cc = 0; cc < NCB; ++cc) {
        int id = idxA[cc * N_PTS + n];
        rd -= (double)cbase[((size_t)cc * KCB + id) * DIM + lane];
    }
    double dir = -rd;                               // z_hard - z
    double rv = fma(1e-3, (double)noise[e], dir);
    double srv = rv * rv, sdir = dir * dir;
#pragma unroll
    for (int off = 32; off >= 1; off >>= 1) {
        srv  += __shfl_xor(srv, off);
        sdir += __shfl_xor(sdir, off);
    }
    double em = sqrt(sdir);
    double nn = sqrt(srv); nn = nn > 1e-12 ? nn : 1e-12;
    out[e] = (float)(zd + em * rv / nn);
}

// ---------------- histogram + idx output (as float32) ------------------------
__global__ __launch_bounds__(256) void hist_kernel(
    const int* __restrict__ idxA, float* __restrict__ out_idx, int* __restrict__ counts)
{
    int t = blockIdx.x * 256 + threadIdx.x;        // C*N, grid 1024
    int v = idxA[t];
    out_idx[t] = (float)v;
    atomicAdd(&counts[(t >> 16) * KCB + v], 1);
}

// ---------------- perplexity -------------------------------------------------
__global__ __launch_bounds__(1024) void perp_kernel(const int* __restrict__ counts,
                                                    float* __restrict__ out)
{
    __shared__ double red[16];
    int tid = threadIdx.x, lane = tid & 63, w = tid >> 6;
    for (int c = 0; c < NCB; ++c) {
        double p = (double)counts[c * KCB + tid] / (double)N_PTS;
        double v = p * log(p + 1e-10);
#pragma unroll
        for (int off = 32; off >= 1; off >>= 1) v += __shfl_xor(v, off);
        if (lane == 0) red[w] = v;
        __syncthreads();
        if (tid == 0) {
            double ssum = 0.0;
            for (int i = 0; i < 16; ++i) ssum += red[i];
            out[c] = (float)exp(-ssum);
        }
        __syncthreads();
    }
}

extern "C" void kernel_launch(void* const* d_in, const int* in_sizes, int n_in,
                              void* d_out, int out_size, void* d_ws, size_t ws_size,
                              hipStream_t stream)
{
    const float* z     = (const float*)d_in[0];
    const float* cbook = (const float*)d_in[1];   // [C,K,D]
    const float* noise = (const float*)d_in[2];
    float* out = (float*)d_out;
    char* ws = (char*)d_ws;

    // rem scratch = d_out's z_q region (16MB), overwritten by zq at the end.
    float* rem = out;

    // ws layout (~23.6 MB)
    unsigned short* remh = (unsigned short*)(ws);                // N*D bf16  8,388,608
    unsigned short* reml = (unsigned short*)(ws + 8388608);      // N*D bf16  8,388,608
    unsigned short* cbh  = (unsigned short*)(ws + 16777216);     // C*K*D       524,288
    unsigned short* cbl  = (unsigned short*)(ws + 17301504);     // C*K*D       524,288
    int*   idxA     = (int*)  (ws + 17825792);                   // C*N       1,048,576
    float* cnp      = (float*)(ws + 18874368);                   // C*K          16,384
    int*   counts   = (int*)  (ws + 18890752);                   // C*K          16,384
    float* srr      = (float*)(ws + 18907136);                   // N           262,144
    int*   flagcnt  = (int*)  (ws + 19169280);                   // 4 (+pad)        256
    int*   flaglist = (int*)  (ws + 19169536);                   // N           262,144
    float* cbT      = (float*)(ws + 19431680);                   // C*D*K f32 4,194,304

    prep_kernel<<<16, 256, 0, stream>>>(cbook, cnp, cbh, cbl, cbT, counts, flagcnt);

    for (int c = 0; c < NCB; ++c) {
        const float* cb_prev = (c == 0) ? nullptr : cbook + (size_t)(c - 1) * KCB * DIM;
        const int*   ix_prev = (c == 0) ? nullptr : idxA + (size_t)(c - 1) * N_PTS;
        const float* usrc    = (c == 0) ? z : rem;
        uprr_kernel<<<N_PTS / 4, 256, 0, stream>>>(
            usrc, cb_prev, ix_prev, rem, remh, reml, srr);
        dist_kernel<<<N_PTS / 128, 256, 0, stream>>>(
            remh, reml, cbh + (size_t)c * KCB * DIM, cbl + (size_t)c * KCB * DIM,
            cnp + c * KCB, srr, idxA + (size_t)c * N_PTS, flagcnt + c, flaglist);
        fixup_kernel<<<512, 256, 0, stream>>>(
            rem, srr, cbT + (size_t)c * DIM * KCB, cnp + c * KCB,
            idxA + (size_t)c * N_PTS, flagcnt + c, flaglist);
    }

    zq_kernel<<<N_PTS / 4, 256, 0, stream>>>(z, noise, cbook, idxA, out);
    hist_kernel<<<NCB * N_PTS / 256, 256, 0, stream>>>(
        idxA, out + (size_t)N_PTS * DIM, counts);
    perp_kernel<<<1, 1024, 0, stream>>>(
        counts, out + (size_t)N_PTS * DIM + (size_t)NCB * N_PTS);
}